// Round 9
// baseline (516.777 us; speedup 1.0000x reference)
//
#include <hip/hip_runtime.h>
#include <math.h>

#define NN 128
#define FF 64
#define KK 50
#define PT 8
#define EPSV 1e-6f

// ws layout (floats):
// dws: [B*N*N]      off 0         (524288)
// T:   [B*N*N]      off 524288
// wu:  [3*50*64*2]  off 1048576
// C:   [B*N*3*64]   off 2097152   (also used as "usg" accumulator before k_epi)
// Fr:  [B*N*3]      off 2883584

__device__ __forceinline__ float softplus_fast(float z) {
    float e = __expf(-fabsf(z));
    float l = __logf(1.f + e);
    return fmaxf(z, 0.f) + l;
}

__global__ __launch_bounds__(256) void k_dist(const float* __restrict__ xs, float* __restrict__ dws)
{
    int tid = blockIdx.x * 256 + threadIdx.x;
    int b = tid >> 14;
    int rem = tid & 16383;
    int i = rem >> 7, a = rem & 127;
    const float* xb = xs + b * (NN * 3);
    float dx = xb[i*3+0] - xb[a*3+0];
    float dy = xb[i*3+1] - xb[a*3+1];
    float dz = xb[i*3+2] - xb[a*3+2];
    dws[tid] = sqrtf(dx*dx + dy*dy + dz*dz + EPSV);
}

// build (w, u) pairs for bwd: u[l][k][f] = 2*gamma*mu_k * W1l[k][f]
__global__ __launch_bounds__(256) void k_prep(
    const float* __restrict__ W1a, const float* __restrict__ W1b, const float* __restrict__ W1c,
    const float* __restrict__ mus, const float* __restrict__ gamma,
    float2* __restrict__ wu)
{
    int idx = blockIdx.x * 256 + threadIdx.x;   // 3*50*64 = 9600
    if (idx < 3 * KK * FF) {
        int l = idx / (KK * FF), r = idx - l * (KK * FF);
        int k = r >> 6;
        const float* W = (l == 0) ? W1a : (l == 1) ? W1b : W1c;
        float w = W[r];
        wu[idx] = make_float2(w, 2.f * gamma[0] * mus[k] * w);
    }
}

// ------- forward pair pass: unordered pairs, f-lane, W1 in registers -------
// block = 512 thr = 8 waves = 8 consecutive atoms. wave=atom i, offsets 1..64.
// i-side softplus sums -> registers (double); a-side -> us_lds window -> global atomics.
__global__ __launch_bounds__(512, 2) void k_fwdp(
    const float* __restrict__ dws,
    const float* __restrict__ mus, const float* __restrict__ gamma,
    const float* __restrict__ W1a, const float* __restrict__ W1b, const float* __restrict__ W1c,
    const float* __restrict__ b1a, const float* __restrict__ b1b, const float* __restrict__ b1c,
    float* __restrict__ usg)
{
    __shared__ float us_lds[3][72][64];   // 55296 B, a_local in [1,71]
    __shared__ float rbfs[8][KK][PT];     // 12800 B
    __shared__ float dsh[8][PT];
    __shared__ float mus_s[64];

    int tid = threadIdx.x;
    float* uz = &us_lds[0][0][0];
    for (int idx = tid; idx < 3 * 72 * 64; idx += 512) uz[idx] = 0.f;
    if (tid < KK) mus_s[tid] = mus[tid];

    int wave = tid >> 6, lane = tid & 63;
    int base = blockIdx.x * 8;
    int atom = base + wave;
    int b = atom >> 7, i = atom & 127;
    float gam = gamma[0];

    // per-lane W1 columns in registers (k fully unrolled everywhere below)
    float w0[KK], w1[KK], w2[KK];
    #pragma unroll
    for (int k = 0; k < KK; ++k) {
        w0[k] = W1a[(k << 6) + lane];
        w1[k] = W1b[(k << 6) + lane];
        w2[k] = W1c[(k << 6) + lane];
    }
    float bb0 = b1a[lane], bb1 = b1b[lane], bb2 = b1c[lane];
    const float* drow = dws + (atom << 7);
    double usd0 = 0.0, usd1 = 0.0, usd2 = 0.0;
    __syncthreads();   // us_lds zeroed, mus_s ready

    #pragma unroll 1
    for (int t = 0; t < 8; ++t) {
        if (lane < PT) {
            int off = 1 + t * PT + lane;
            dsh[wave][lane] = drow[(i + off) & 127];
        }
        #pragma unroll
        for (int pass = 0; pass < 7; ++pass) {
            int idx = lane + (pass << 6);
            if (idx < KK * PT) {
                int k = idx >> 3, p = idx & 7;
                float dd = dsh[wave][p] - mus_s[k];
                rbfs[wave][k][p] = __expf(-gam * dd * dd);
            }
        }
        float z0[PT], z1[PT], z2[PT];
        #pragma unroll
        for (int p = 0; p < PT; ++p) { z0[p] = bb0; z1[p] = bb1; z2[p] = bb2; }
        #pragma unroll
        for (int k = 0; k < KK; ++k) {
            float rr[PT];
            *(float4*)&rr[0] = *(const float4*)&rbfs[wave][k][0];
            *(float4*)&rr[4] = *(const float4*)&rbfs[wave][k][4];
            #pragma unroll
            for (int p = 0; p < PT; ++p) {
                z0[p] = fmaf(rr[p], w0[k], z0[p]);
                z1[p] = fmaf(rr[p], w1[k], z1[p]);
                z2[p] = fmaf(rr[p], w2[k], z2[p]);
            }
        }
        float ut0 = 0.f, ut1 = 0.f, ut2 = 0.f;
        #pragma unroll
        for (int p = 0; p < PT; ++p) {
            int off = 1 + t * PT + p;
            bool valid = (off < 64) || (i < 64);
            float sp0 = softplus_fast(z0[p]);
            float sp1 = softplus_fast(z1[p]);
            float sp2 = softplus_fast(z2[p]);
            sp0 = valid ? sp0 : 0.f;
            sp1 = valid ? sp1 : 0.f;
            sp2 = valid ? sp2 : 0.f;
            ut0 += sp0; ut1 += sp1; ut2 += sp2;
            int al = wave + off;              // a_local in [1,71]
            atomicAdd(&us_lds[0][al][lane], sp0);
            atomicAdd(&us_lds[1][al][lane], sp1);
            atomicAdd(&us_lds[2][al][lane], sp2);
        }
        usd0 += (double)ut0; usd1 += (double)ut1; usd2 += (double)ut2;
    }

    // i-side sums -> global accumulator (atomic: other blocks also add here)
    atomicAdd(&usg[atom * 192 + lane],        (float)usd0);
    atomicAdd(&usg[atom * 192 + 64 + lane],   (float)usd1);
    atomicAdd(&usg[atom * 192 + 128 + lane],  (float)usd2);
    __syncthreads();

    // a-side window -> global
    int bl = base & 127;
    for (int idx = tid; idx < 3 * 72 * 64; idx += 512) {
        int l = idx / 4608;                 // 72*64
        int r = idx - l * 4608;
        int al = r >> 6, f2 = r & 63;
        if (al >= 1) {
            float v = uz[idx];
            int agl = (bl + al) & 127;
            atomicAdd(&usg[(((b << 7) + agl) * 192) + l * 64 + f2], v);
        }
    }
}

// ------- per-atom epilogue: reads usg, writes C in place (same buffer) -------
__global__ __launch_bounds__(256) void k_epi(
    float* __restrict__ CU,
    const float* __restrict__ W2a, const float* __restrict__ W2b, const float* __restrict__ W2c,
    const float* __restrict__ b2a, const float* __restrict__ b2b, const float* __restrict__ b2c,
    const float* __restrict__ Wenc, const float* __restrict__ benc,
    const float* __restrict__ Wt1, const float* __restrict__ bt1, const float* __restrict__ Wt2)
{
    __shared__ double epid[4][FF];
    __shared__ float  epif[4][FF];
    int tid = threadIdx.x;
    int wave = tid >> 6, lane = tid & 63, f = lane;
    int atom = blockIdx.x * 4 + wave;

    double us0 = (double)CU[atom * 192 + lane];
    double us1 = (double)CU[atom * 192 + 64 + lane];
    double us2 = (double)CU[atom * 192 + 128 + lane];

    double wf0, wf1, wf2;
    {
        epid[wave][lane] = us0;
        double acc = 0.0;
        for (int m = 0; m < 64; ++m) acc += epid[wave][m] * (double)W2a[m*64 + f];
        wf0 = 1.0 + acc + 127.0 * (double)b2a[f];

        epid[wave][lane] = us1;
        double acc1 = 0.0;
        for (int m = 0; m < 64; ++m) acc1 += epid[wave][m] * (double)W2b[m*64 + f];
        wf1 = 1.0 + acc1 + 127.0 * (double)b2b[f];

        epid[wave][lane] = us2;
        double acc2 = 0.0;
        for (int m = 0; m < 64; ++m) acc2 += epid[wave][m] * (double)W2c[m*64 + f];
        wf2 = 1.0 + acc2 + 127.0 * (double)b2c[f];
    }
    double h0 = (double)Wenc[f] + (double)benc[f];
    double h  = h0 * wf0 * wf1 * wf2;
    epid[wave][lane] = h;
    double pre = (double)bt1[lane];
    for (int m = 0; m < 64; ++m) pre += epid[wave][m] * (double)Wt1[m*64 + lane];
    double tv = tanh(pre);
    float gv = (float)((1.0 - tv * tv) * (double)Wt2[lane]);

    float p1 = (float)(h0 * wf1 * wf2);
    float p2 = (float)(h0 * wf0 * wf2);
    float p3 = (float)(h0 * wf0 * wf1);

    epif[wave][lane] = gv;
    float dv = 0.f;
    for (int m = 0; m < 64; ++m) dv = fmaf(epif[wave][m], Wt1[lane*64 + m], dv);

    float* co = CU + atom * 192;
    epif[wave][lane] = dv * p1;
    float c0 = 0.f;
    for (int m = 0; m < 64; ++m) c0 = fmaf(epif[wave][m], W2a[lane*64 + m], c0);
    co[lane] = c0;

    epif[wave][lane] = dv * p2;
    float c1 = 0.f;
    for (int m = 0; m < 64; ++m) c1 = fmaf(epif[wave][m], W2b[lane*64 + m], c1);
    co[64 + lane] = c1;

    epif[wave][lane] = dv * p3;
    float c2 = 0.f;
    for (int m = 0; m < 64; ++m) c2 = fmaf(epif[wave][m], W2c[lane*64 + m], c2);
    co[128 + lane] = c2;
}

// ------- backward: f-lane layout, unordered pairs, PT=8 pair register tile -------
__global__ __launch_bounds__(1024, 4) void k_bwd(
    const float* __restrict__ dws,
    const float* __restrict__ mus, const float* __restrict__ gamma,
    const float2* __restrict__ wu,
    const float* __restrict__ b1a, const float* __restrict__ b1b, const float* __restrict__ b1c,
    const float* __restrict__ C, float* __restrict__ T)
{
    __shared__ float2 wus[3 * KK * FF];    // 76800 B  [l][k][f]
    __shared__ float  rbfs[16][KK][PT];    // 25600 B
    __shared__ float  dsh[16][PT];
    __shared__ float  mus_s[64];

    int tid = threadIdx.x;
    for (int idx = tid; idx < 3 * KK * FF; idx += 1024) wus[idx] = wu[idx];
    if (tid < KK) mus_s[tid] = mus[tid];
    __syncthreads();

    int wave = tid >> 6, lane = tid & 63;
    int atom = blockIdx.x * 16 + wave;
    int b = atom >> 7, i = atom & 127;
    float gam = gamma[0];
    float n2g = -2.f * gam;
    const float* drow = dws + (atom << 7);
    const float* ci = C + atom * 192;
    float ci0 = ci[lane], ci1 = ci[64 + lane], ci2 = ci[128 + lane];
    float bb0 = b1a[lane], bb1 = b1b[lane], bb2 = b1c[lane];
    float* Tb = T + ((size_t)b << 14);

    for (int t = 0; t < 8; ++t) {
        if (lane < PT) {
            int off = 1 + t * PT + lane;
            dsh[wave][lane] = drow[(i + off) & 127];
        }
        #pragma unroll
        for (int pass = 0; pass < 7; ++pass) {
            int idx = lane + (pass << 6);
            if (idx < KK * PT) {
                int k = idx >> 3, p = idx & 7;
                float dd = dsh[wave][p] - mus_s[k];
                rbfs[wave][k][p] = __expf(-gam * dd * dd);
            }
        }
        float z0[PT], z1[PT], z2[PT], v0[PT], v1[PT], v2[PT];
        #pragma unroll
        for (int p = 0; p < PT; ++p) {
            z0[p] = 0.f; z1[p] = 0.f; z2[p] = 0.f;
            v0[p] = 0.f; v1[p] = 0.f; v2[p] = 0.f;
        }
        #pragma unroll 2
        for (int k = 0; k < KK; ++k) {
            float2 w0 = wus[(k << 6) + lane];
            float2 w1 = wus[KK * FF + (k << 6) + lane];
            float2 w2 = wus[2 * KK * FF + (k << 6) + lane];
            float rr[PT];
            {
                const float4* rp4 = (const float4*)(&rbfs[wave][k][0]);
                float4 a0 = rp4[0], a1 = rp4[1];
                *(float4*)&rr[0] = a0; *(float4*)&rr[4] = a1;
            }
            #pragma unroll
            for (int p = 0; p < PT; ++p) {
                z0[p] = fmaf(rr[p], w0.x, z0[p]);
                v0[p] = fmaf(rr[p], w0.y, v0[p]);
                z1[p] = fmaf(rr[p], w1.x, z1[p]);
                v1[p] = fmaf(rr[p], w1.y, v1[p]);
                z2[p] = fmaf(rr[p], w2.x, z2[p]);
                v2[p] = fmaf(rr[p], w2.y, v2[p]);
            }
        }
        float vmine = 0.f;
        #pragma unroll
        for (int p = 0; p < PT; ++p) {
            float d = dsh[wave][p];
            float n2gd = n2g * d;
            float zb0 = z0[p] + bb0, zb1 = z1[p] + bb1, zb2 = z2[p] + bb2;
            float s0 = __builtin_amdgcn_rcpf(1.f + __expf(-zb0));
            float s1 = __builtin_amdgcn_rcpf(1.f + __expf(-zb1));
            float s2 = __builtin_amdgcn_rcpf(1.f + __expf(-zb2));
            float y0 = fmaf(n2gd, z0[p], v0[p]);
            float y1 = fmaf(n2gd, z1[p], v1[p]);
            float y2 = fmaf(n2gd, z2[p], v2[p]);
            float g0 = s0 * y0, g1 = s1 * y1, g2 = s2 * y2;
            int a = (i + 1 + t * PT + p) & 127;
            const float* ca = C + (((b << 7) + a) * 192);
            float red = fmaf(ci0, g0, fmaf(ci1, g1, ci2 * g2));
            red = fmaf(ca[lane], g0, red);
            red = fmaf(ca[64 + lane], g1, red);
            red = fmaf(ca[128 + lane], g2, red);
            #pragma unroll
            for (int o = 1; o < 64; o <<= 1) red += __shfl_xor(red, o);
            if (lane == p) vmine = red;
        }
        if (lane < PT) {
            int off = 1 + t * PT + lane;
            if (off < 64 || i < 64) {
                int a = (i + off) & 127;
                Tb[(i << 7) + a] = vmine;
                Tb[(a << 7) + i] = vmine;
            }
        }
    }
}

__global__ __launch_bounds__(256) void k_force(
    const float* __restrict__ xs, const float* __restrict__ dws,
    const float* __restrict__ T, float* __restrict__ Fr)
{
    int tid = threadIdx.x;
    int wave = tid >> 6, lane = tid & 63;
    int atom = blockIdx.x * 4 + wave;
    int i = atom & 127;
    int b = atom >> 7;
    const float* xb = xs + b * (NN * 3);
    float xi0 = xb[i*3], xi1 = xb[i*3+1], xi2 = xb[i*3+2];
    const float* drow = dws + (atom << 7);
    const float* trow = T + (atom << 7);
    float fx = 0.f, fy = 0.f, fz = 0.f;
    for (int it = lane; it < 127; it += 64) {
        int aa = (i + 1 + it) & 127;
        float coef = trow[aa] / drow[aa];
        fx += coef * (xi0 - xb[aa*3]);
        fy += coef * (xi1 - xb[aa*3+1]);
        fz += coef * (xi2 - xb[aa*3+2]);
    }
    #pragma unroll
    for (int off = 1; off < 64; off <<= 1) {
        fx += __shfl_xor(fx, off);
        fy += __shfl_xor(fy, off);
        fz += __shfl_xor(fz, off);
    }
    if (lane == 0) {
        Fr[atom*3]   = fx;
        Fr[atom*3+1] = fy;
        Fr[atom*3+2] = fz;
    }
}

__global__ __launch_bounds__(128) void k_out(const float* __restrict__ Fr, float* __restrict__ out)
{
    __shared__ float rs[3][128];
    int b = blockIdx.x, n = threadIdx.x;
    float g0 = Fr[(b*128+n)*3], g1 = Fr[(b*128+n)*3+1], g2 = Fr[(b*128+n)*3+2];
    rs[0][n] = g0; rs[1][n] = g1; rs[2][n] = g2;
    __syncthreads();
    for (int s = 64; s > 0; s >>= 1) {
        if (n < s) {
            rs[0][n] += rs[0][n+s];
            rs[1][n] += rs[1][n+s];
            rs[2][n] += rs[2][n+s];
        }
        __syncthreads();
    }
    float m0 = rs[0][0] * (1.f/128.f);
    float m1 = rs[1][0] * (1.f/128.f);
    float m2 = rs[2][0] * (1.f/128.f);
    out[b*384 + n*3 + 0] = m0 - g0;
    out[b*384 + n*3 + 1] = m1 - g1;
    out[b*384 + n*3 + 2] = m2 - g2;
}

extern "C" void kernel_launch(void* const* d_in, const int* in_sizes, int n_in,
                              void* d_out, int out_size, void* d_ws, size_t ws_size,
                              hipStream_t stream)
{
    const float* xs   = (const float*)d_in[1];
    const float* mus  = (const float*)d_in[2];
    const float* gam  = (const float*)d_in[3];
    const float* Wenc = (const float*)d_in[4];
    const float* benc = (const float*)d_in[5];
    const float* W1a  = (const float*)d_in[6];
    const float* b1a  = (const float*)d_in[7];
    const float* W2a  = (const float*)d_in[8];
    const float* b2a  = (const float*)d_in[9];
    const float* W1b  = (const float*)d_in[10];
    const float* b1b  = (const float*)d_in[11];
    const float* W2b  = (const float*)d_in[12];
    const float* b2b  = (const float*)d_in[13];
    const float* W1c  = (const float*)d_in[14];
    const float* b1c  = (const float*)d_in[15];
    const float* W2c  = (const float*)d_in[16];
    const float* b2c  = (const float*)d_in[17];
    const float* Wt1  = (const float*)d_in[18];
    const float* bt1  = (const float*)d_in[19];
    const float* Wt2  = (const float*)d_in[20];

    float* ws  = (float*)d_ws;
    float* dws = ws;
    float* T   = ws + 524288;
    float2* wu = (float2*)(ws + 1048576);
    float* C   = ws + 2097152;          // doubles as usg accumulator
    float* Fr  = ws + 2883584;
    float* out = (float*)d_out;

    hipMemsetAsync(C, 0, 786432 * sizeof(float), stream);
    k_dist <<<2048, 256, 0, stream>>>(xs, dws);
    k_prep <<<38, 256, 0, stream>>>(W1a, W1b, W1c, mus, gam, wu);
    k_fwdp <<<512, 512, 0, stream>>>(dws, mus, gam, W1a, W1b, W1c, b1a, b1b, b1c, C);
    k_epi  <<<1024, 256, 0, stream>>>(C, W2a, W2b, W2c, b2a, b2b, b2c,
                                      Wenc, benc, Wt1, bt1, Wt2);
    k_bwd  <<<256, 1024, 0, stream>>>(dws, mus, gam, wu, b1a, b1b, b1c, C, T);
    k_force<<<1024, 256, 0, stream>>>(xs, dws, T, Fr);
    k_out  <<<32, 128, 0, stream>>>(Fr, out);
}

// Round 10
// 378.499 us; speedup vs baseline: 1.3653x; 1.3653x over previous
//
#include <hip/hip_runtime.h>
#include <math.h>

#define NN 128
#define FF 64
#define KK 50
#define PT 8
#define EPSV 1e-6f

// ws layout (floats):
// dws: [B*N*N]      off 0         (524288)
// T:   [B*N*N]      off 524288
// wu:  [3*50*64*2]  off 1048576
// C:   [B*N*3*64]   off 2097152
// Fr:  [B*N*3]      off 2883584

__device__ __forceinline__ float softplus_fast(float z) {
    float e = __expf(-fabsf(z));
    float l = __logf(1.f + e);
    return fmaxf(z, 0.f) + l;
}

__global__ __launch_bounds__(256) void k_dist(const float* __restrict__ xs, float* __restrict__ dws)
{
    int tid = blockIdx.x * 256 + threadIdx.x;
    int b = tid >> 14;
    int rem = tid & 16383;
    int i = rem >> 7, a = rem & 127;
    const float* xb = xs + b * (NN * 3);
    float dx = xb[i*3+0] - xb[a*3+0];
    float dy = xb[i*3+1] - xb[a*3+1];
    float dz = xb[i*3+2] - xb[a*3+2];
    dws[tid] = sqrtf(dx*dx + dy*dy + dz*dz + EPSV);
}

// build (w, u) pairs for bwd: u[l][k][f] = 2*gamma*mu_k * W1l[k][f]
__global__ __launch_bounds__(256) void k_prep(
    const float* __restrict__ W1a, const float* __restrict__ W1b, const float* __restrict__ W1c,
    const float* __restrict__ mus, const float* __restrict__ gamma,
    float2* __restrict__ wu)
{
    int idx = blockIdx.x * 256 + threadIdx.x;   // 3*50*64 = 9600
    if (idx < 3 * KK * FF) {
        int l = idx / (KK * FF), r = idx - l * (KK * FF);
        int k = r >> 6;
        const float* W = (l == 0) ? W1a : (l == 1) ? W1b : W1c;
        float w = W[r];
        wu[idx] = make_float2(w, 2.f * gamma[0] * mus[k] * w);
    }
}

// ------- forward (+ fused per-atom epilogue): W1 in registers, rbf via LDS broadcast -------
__global__ __launch_bounds__(512, 2) void k_fwd(
    const float* __restrict__ dws,
    const float* __restrict__ mus, const float* __restrict__ gamma,
    const float* __restrict__ W1a, const float* __restrict__ W1b, const float* __restrict__ W1c,
    const float* __restrict__ b1a, const float* __restrict__ b1b, const float* __restrict__ b1c,
    const float* __restrict__ W2a, const float* __restrict__ W2b, const float* __restrict__ W2c,
    const float* __restrict__ b2a, const float* __restrict__ b2b, const float* __restrict__ b2c,
    const float* __restrict__ Wenc, const float* __restrict__ benc,
    const float* __restrict__ Wt1, const float* __restrict__ bt1, const float* __restrict__ Wt2,
    float* __restrict__ Cout)
{
    __shared__ float  rbfs[8][KK][16];    // 25600 B
    __shared__ float  dsh[8][16];
    __shared__ float  mus_s[64];
    __shared__ double epid[8][FF];
    __shared__ float  epif[8][FF];

    int tid = threadIdx.x;
    if (tid < KK) mus_s[tid] = mus[tid];

    int wave = tid >> 6, lane = tid & 63, f = lane;
    int atom = blockIdx.x * 8 + wave;
    int i = atom & 127;
    float gam = gamma[0];

    // per-lane W1 columns in registers (k-loop fully unrolled below)
    float w0[KK], w1[KK], w2[KK];
    #pragma unroll
    for (int k = 0; k < KK; ++k) {
        w0[k] = W1a[(k << 6) + lane];
        w1[k] = W1b[(k << 6) + lane];
        w2[k] = W1c[(k << 6) + lane];
    }
    float bb0 = b1a[f], bb1 = b1b[f], bb2 = b1c[f];
    double us0 = 0.0, us1 = 0.0, us2 = 0.0;
    const float* drow = dws + (atom << 7);
    __syncthreads();

    #pragma unroll 1
    for (int t = 0; t < 8; ++t) {
        if (lane < 16) {
            int aa = (i + 1 + 16 * t + lane) & 127;
            dsh[wave][lane] = drow[aa];
        }
        #pragma unroll
        for (int pass = 0; pass < 13; ++pass) {
            int idx = lane + (pass << 6);
            int k = idx >> 4, p = idx & 15;
            if (k < KK) {
                float dd = dsh[wave][p] - mus_s[k];
                rbfs[wave][k][p] = __expf(-gam * dd * dd);
            }
        }
        float z0[16], z1[16], z2[16];
        #pragma unroll
        for (int p = 0; p < 16; ++p) { z0[p] = bb0; z1[p] = bb1; z2[p] = bb2; }
        #pragma unroll
        for (int k = 0; k < KK; ++k) {
            float rr[16];
            *(float4*)&rr[0]  = *(const float4*)&rbfs[wave][k][0];
            *(float4*)&rr[4]  = *(const float4*)&rbfs[wave][k][4];
            *(float4*)&rr[8]  = *(const float4*)&rbfs[wave][k][8];
            *(float4*)&rr[12] = *(const float4*)&rbfs[wave][k][12];
            #pragma unroll
            for (int p = 0; p < 16; ++p) {
                z0[p] = fmaf(rr[p], w0[k], z0[p]);
                z1[p] = fmaf(rr[p], w1[k], z1[p]);
                z2[p] = fmaf(rr[p], w2[k], z2[p]);
            }
        }
        int base = 16 * t;
        #pragma unroll
        for (int p = 0; p < 16; ++p) {
            if (base + p < 127) {
                us0 += (double)softplus_fast(z0[p]);
                us1 += (double)softplus_fast(z1[p]);
                us2 += (double)softplus_fast(z2[p]);
            }
        }
    }

    // per-atom epilogue (wave-local, double precision for h/pre path)
    double wf0, wf1, wf2;
    {
        epid[wave][lane] = us0;
        double acc = 0.0;
        for (int m = 0; m < 64; ++m) acc += epid[wave][m] * (double)W2a[m*64 + f];
        wf0 = 1.0 + acc + 127.0 * (double)b2a[f];

        epid[wave][lane] = us1;
        double acc1 = 0.0;
        for (int m = 0; m < 64; ++m) acc1 += epid[wave][m] * (double)W2b[m*64 + f];
        wf1 = 1.0 + acc1 + 127.0 * (double)b2b[f];

        epid[wave][lane] = us2;
        double acc2 = 0.0;
        for (int m = 0; m < 64; ++m) acc2 += epid[wave][m] * (double)W2c[m*64 + f];
        wf2 = 1.0 + acc2 + 127.0 * (double)b2c[f];
    }
    double h0 = (double)Wenc[f] + (double)benc[f];
    double h  = h0 * wf0 * wf1 * wf2;
    epid[wave][lane] = h;
    double pre = (double)bt1[lane];
    for (int m = 0; m < 64; ++m) pre += epid[wave][m] * (double)Wt1[m*64 + lane];
    double tv = tanh(pre);
    float gv = (float)((1.0 - tv * tv) * (double)Wt2[lane]);

    float p1 = (float)(h0 * wf1 * wf2);   // pairs with layer a
    float p2 = (float)(h0 * wf0 * wf2);   // layer b
    float p3 = (float)(h0 * wf0 * wf1);   // layer c

    // fused: dv = g @ Wt1^T
    epif[wave][lane] = gv;
    float dv = 0.f;
    for (int m = 0; m < 64; ++m) dv = fmaf(epif[wave][m], Wt1[lane*64 + m], dv);

    float* co = Cout + atom * 192;
    epif[wave][lane] = dv * p1;
    float c0 = 0.f;
    for (int m = 0; m < 64; ++m) c0 = fmaf(epif[wave][m], W2a[lane*64 + m], c0);
    co[lane] = c0;

    epif[wave][lane] = dv * p2;
    float c1 = 0.f;
    for (int m = 0; m < 64; ++m) c1 = fmaf(epif[wave][m], W2b[lane*64 + m], c1);
    co[64 + lane] = c1;

    epif[wave][lane] = dv * p3;
    float c2 = 0.f;
    for (int m = 0; m < 64; ++m) c2 = fmaf(epif[wave][m], W2c[lane*64 + m], c2);
    co[128 + lane] = c2;
}

// ------- backward: f-lane layout, unordered pairs, PT=8 pair register tile -------
__global__ __launch_bounds__(1024, 4) void k_bwd(
    const float* __restrict__ dws,
    const float* __restrict__ mus, const float* __restrict__ gamma,
    const float2* __restrict__ wu,
    const float* __restrict__ b1a, const float* __restrict__ b1b, const float* __restrict__ b1c,
    const float* __restrict__ C, float* __restrict__ T)
{
    __shared__ float2 wus[3 * KK * FF];    // 76800 B  [l][k][f]
    __shared__ float  rbfs[16][KK][PT];    // 25600 B
    __shared__ float  dsh[16][PT];
    __shared__ float  mus_s[64];

    int tid = threadIdx.x;
    for (int idx = tid; idx < 3 * KK * FF; idx += 1024) wus[idx] = wu[idx];
    if (tid < KK) mus_s[tid] = mus[tid];
    __syncthreads();

    int wave = tid >> 6, lane = tid & 63;
    int atom = blockIdx.x * 16 + wave;
    int b = atom >> 7, i = atom & 127;
    float gam = gamma[0];
    float n2g = -2.f * gam;
    const float* drow = dws + (atom << 7);
    const float* ci = C + atom * 192;
    float ci0 = ci[lane], ci1 = ci[64 + lane], ci2 = ci[128 + lane];
    float bb0 = b1a[lane], bb1 = b1b[lane], bb2 = b1c[lane];
    float* Tb = T + ((size_t)b << 14);

    for (int t = 0; t < 8; ++t) {
        if (lane < PT) {
            int off = 1 + t * PT + lane;
            dsh[wave][lane] = drow[(i + off) & 127];
        }
        #pragma unroll
        for (int pass = 0; pass < 7; ++pass) {
            int idx = lane + (pass << 6);
            if (idx < KK * PT) {
                int k = idx >> 3, p = idx & 7;
                float dd = dsh[wave][p] - mus_s[k];
                rbfs[wave][k][p] = __expf(-gam * dd * dd);
            }
        }
        float z0[PT], z1[PT], z2[PT], v0[PT], v1[PT], v2[PT];
        #pragma unroll
        for (int p = 0; p < PT; ++p) {
            z0[p] = 0.f; z1[p] = 0.f; z2[p] = 0.f;
            v0[p] = 0.f; v1[p] = 0.f; v2[p] = 0.f;
        }
        #pragma unroll 2
        for (int k = 0; k < KK; ++k) {
            float2 w0 = wus[(k << 6) + lane];
            float2 w1 = wus[KK * FF + (k << 6) + lane];
            float2 w2 = wus[2 * KK * FF + (k << 6) + lane];
            float rr[PT];
            {
                const float4* rp4 = (const float4*)(&rbfs[wave][k][0]);
                float4 a0 = rp4[0], a1 = rp4[1];
                *(float4*)&rr[0] = a0; *(float4*)&rr[4] = a1;
            }
            #pragma unroll
            for (int p = 0; p < PT; ++p) {
                z0[p] = fmaf(rr[p], w0.x, z0[p]);
                v0[p] = fmaf(rr[p], w0.y, v0[p]);
                z1[p] = fmaf(rr[p], w1.x, z1[p]);
                v1[p] = fmaf(rr[p], w1.y, v1[p]);
                z2[p] = fmaf(rr[p], w2.x, z2[p]);
                v2[p] = fmaf(rr[p], w2.y, v2[p]);
            }
        }
        float vmine = 0.f;
        #pragma unroll
        for (int p = 0; p < PT; ++p) {
            float d = dsh[wave][p];
            float n2gd = n2g * d;
            float zb0 = z0[p] + bb0, zb1 = z1[p] + bb1, zb2 = z2[p] + bb2;
            float s0 = __builtin_amdgcn_rcpf(1.f + __expf(-zb0));
            float s1 = __builtin_amdgcn_rcpf(1.f + __expf(-zb1));
            float s2 = __builtin_amdgcn_rcpf(1.f + __expf(-zb2));
            float y0 = fmaf(n2gd, z0[p], v0[p]);
            float y1 = fmaf(n2gd, z1[p], v1[p]);
            float y2 = fmaf(n2gd, z2[p], v2[p]);
            float g0 = s0 * y0, g1 = s1 * y1, g2 = s2 * y2;
            int a = (i + 1 + t * PT + p) & 127;
            const float* ca = C + (((b << 7) + a) * 192);
            float red = fmaf(ci0, g0, fmaf(ci1, g1, ci2 * g2));
            red = fmaf(ca[lane], g0, red);
            red = fmaf(ca[64 + lane], g1, red);
            red = fmaf(ca[128 + lane], g2, red);
            #pragma unroll
            for (int o = 1; o < 64; o <<= 1) red += __shfl_xor(red, o);
            if (lane == p) vmine = red;
        }
        if (lane < PT) {
            int off = 1 + t * PT + lane;
            if (off < 64 || i < 64) {
                int a = (i + off) & 127;
                Tb[(i << 7) + a] = vmine;
                Tb[(a << 7) + i] = vmine;
            }
        }
    }
}

__global__ __launch_bounds__(256) void k_force(
    const float* __restrict__ xs, const float* __restrict__ dws,
    const float* __restrict__ T, float* __restrict__ Fr)
{
    int tid = threadIdx.x;
    int wave = tid >> 6, lane = tid & 63;
    int atom = blockIdx.x * 4 + wave;
    int i = atom & 127;
    int b = atom >> 7;
    const float* xb = xs + b * (NN * 3);
    float xi0 = xb[i*3], xi1 = xb[i*3+1], xi2 = xb[i*3+2];
    const float* drow = dws + (atom << 7);
    const float* trow = T + (atom << 7);
    float fx = 0.f, fy = 0.f, fz = 0.f;
    for (int it = lane; it < 127; it += 64) {
        int aa = (i + 1 + it) & 127;
        float coef = trow[aa] / drow[aa];
        fx += coef * (xi0 - xb[aa*3]);
        fy += coef * (xi1 - xb[aa*3+1]);
        fz += coef * (xi2 - xb[aa*3+2]);
    }
    #pragma unroll
    for (int off = 1; off < 64; off <<= 1) {
        fx += __shfl_xor(fx, off);
        fy += __shfl_xor(fy, off);
        fz += __shfl_xor(fz, off);
    }
    if (lane == 0) {
        Fr[atom*3]   = fx;
        Fr[atom*3+1] = fy;
        Fr[atom*3+2] = fz;
    }
}

__global__ __launch_bounds__(128) void k_out(const float* __restrict__ Fr, float* __restrict__ out)
{
    __shared__ float rs[3][128];
    int b = blockIdx.x, n = threadIdx.x;
    float g0 = Fr[(b*128+n)*3], g1 = Fr[(b*128+n)*3+1], g2 = Fr[(b*128+n)*3+2];
    rs[0][n] = g0; rs[1][n] = g1; rs[2][n] = g2;
    __syncthreads();
    for (int s = 64; s > 0; s >>= 1) {
        if (n < s) {
            rs[0][n] += rs[0][n+s];
            rs[1][n] += rs[1][n+s];
            rs[2][n] += rs[2][n+s];
        }
        __syncthreads();
    }
    float m0 = rs[0][0] * (1.f/128.f);
    float m1 = rs[1][0] * (1.f/128.f);
    float m2 = rs[2][0] * (1.f/128.f);
    out[b*384 + n*3 + 0] = m0 - g0;
    out[b*384 + n*3 + 1] = m1 - g1;
    out[b*384 + n*3 + 2] = m2 - g2;
}

extern "C" void kernel_launch(void* const* d_in, const int* in_sizes, int n_in,
                              void* d_out, int out_size, void* d_ws, size_t ws_size,
                              hipStream_t stream)
{
    const float* xs   = (const float*)d_in[1];
    const float* mus  = (const float*)d_in[2];
    const float* gam  = (const float*)d_in[3];
    const float* Wenc = (const float*)d_in[4];
    const float* benc = (const float*)d_in[5];
    const float* W1a  = (const float*)d_in[6];
    const float* b1a  = (const float*)d_in[7];
    const float* W2a  = (const float*)d_in[8];
    const float* b2a  = (const float*)d_in[9];
    const float* W1b  = (const float*)d_in[10];
    const float* b1b  = (const float*)d_in[11];
    const float* W2b  = (const float*)d_in[12];
    const float* b2b  = (const float*)d_in[13];
    const float* W1c  = (const float*)d_in[14];
    const float* b1c  = (const float*)d_in[15];
    const float* W2c  = (const float*)d_in[16];
    const float* b2c  = (const float*)d_in[17];
    const float* Wt1  = (const float*)d_in[18];
    const float* bt1  = (const float*)d_in[19];
    const float* Wt2  = (const float*)d_in[20];

    float* ws  = (float*)d_ws;
    float* dws = ws;
    float* T   = ws + 524288;
    float2* wu = (float2*)(ws + 1048576);
    float* C   = ws + 2097152;
    float* Fr  = ws + 2883584;
    float* out = (float*)d_out;

    k_dist <<<2048, 256, 0, stream>>>(xs, dws);
    k_prep <<<38, 256, 0, stream>>>(W1a, W1b, W1c, mus, gam, wu);
    k_fwd  <<<512, 512, 0, stream>>>(dws, mus, gam, W1a, W1b, W1c, b1a, b1b, b1c,
                                     W2a, W2b, W2c, b2a, b2b, b2c, Wenc, benc,
                                     Wt1, bt1, Wt2, C);
    k_bwd  <<<256, 1024, 0, stream>>>(dws, mus, gam, wu, b1a, b1b, b1c, C, T);
    k_force<<<1024, 256, 0, stream>>>(xs, dws, T, Fr);
    k_out  <<<32, 128, 0, stream>>>(Fr, out);
}